// Round 5
// baseline (120.809 us; speedup 1.0000x reference)
//
#include <hip/hip_runtime.h>

#define B_SZ 8192

// ---------------- masks (exact 1.5-entmax via bisection) + fused params ----------------
struct MaskArgs {
  const float* fm[6];
  const float* cp[6];
  const float* lr[6];
  float* out_masks;  // d_out base
  float4* prm;       // fused params {c10, ml0, ml1, 0}
  float* cstf;       // flat per-output 0.5*sum(ml): level d at 2*cstOff[d]
};

__device__ __forceinline__ float wave_max(float v) {
#pragma unroll
  for (int o = 32; o > 0; o >>= 1) v = fmaxf(v, __shfl_xor(v, o));
  return v;
}
__device__ __forceinline__ float wave_sum(float v) {
#pragma unroll
  for (int o = 32; o > 0; o >>= 1) v += __shfl_xor(v, o);
  return v;
}

__global__ __launch_bounds__(64) void ndt_masks(MaskArgs a) {
  const int maskOff[6] = {524288, 524544, 525060, 526100, 528212, 532564};
  const int prmOff[6]  = {0, 256, 772, 1812, 3924, 8276};
  const int cstOff[6]  = {0, 1, 3, 7, 15, 31};
  int bid = blockIdx.x, lane = threadIdx.x;
  int d = 0, s = bid, n = 1;
  while (s >= n) { s -= n; n <<= 1; ++d; }   // level d, stump s, n = 2^d
  int Fd = 256 + ((d > 0) ? n : 0);

  const float* fm = a.fm[d] + (size_t)s * Fd;
  float y[5];
#pragma unroll
  for (int j = 0; j < 5; ++j) {
    int f = lane + 64 * j;
    y[j] = (f < Fd) ? fm[f] * 0.5f : -3.0e38f;
  }
  float m = fmaxf(fmaxf(fmaxf(y[0], y[1]), fmaxf(y[2], y[3])), y[4]);
  m = wave_max(m);
#pragma unroll
  for (int j = 0; j < 5; ++j) y[j] -= m;

  // solve sum clip(y - tau, 0)^2 = 1 ; tau in [-1, 0], strictly decreasing in tau
  float lo = -1.f, hi = 0.f;
  for (int it = 0; it < 24; ++it) {
    float tau = 0.5f * (lo + hi);
    float ss = 0.f;
#pragma unroll
    for (int j = 0; j < 5; ++j) {
      float v = fmaxf(y[j] - tau, 0.f);
      ss = __builtin_fmaf(v, v, ss);
    }
    ss = wave_sum(ss);
    if (ss >= 1.f) lo = tau; else hi = tau;
  }
  float tau = 0.5f * (lo + hi);

  float* mo = a.out_masks + maskOff[d] + (size_t)s * Fd;
  const float* cp = a.cp[d] + (size_t)s * Fd * 2;
  const float* lr = a.lr[d] + (size_t)s * Fd * 2;
  float4* pr = a.prm + prmOff[d] + (size_t)s * Fd;
  float sum0 = 0.f, sum1 = 0.f;
#pragma unroll
  for (int j = 0; j < 5; ++j) {
    int f = lane + 64 * j;
    if (f < Fd) {
      float v = fmaxf(y[j] - tau, 0.f);
      float mk = v * v;
      mo[f] = mk;
      float c0 = cp[2 * f], c1 = cp[2 * f + 1];
      float ml0 = lr[2 * f] * mk, ml1 = lr[2 * f + 1] * mk;
      sum0 += ml0;
      sum1 += ml1;
      pr[f] = make_float4(c1 - c0, ml0, ml1, 0.f);
    }
  }
  sum0 = wave_sum(sum0);
  sum1 = wave_sum(sum1);
  if (lane == 0) {
    a.cstf[2 * (cstOff[d] + s)] = 0.5f * sum0;
    a.cstf[2 * (cstOff[d] + s) + 1] = 0.5f * sum1;
  }
}

// 2-elem entmax15 closed form: t = c10 - x; tc = clamp(t,-2,2);
// e = tc*sqrt(0.125 - tc^2/64); p0 = 0.5+e, p1 = 0.5-e.
__device__ __forceinline__ float entpair(float c10, float xv) {
  float t = c10 - xv;
  float tc = __builtin_amdgcn_fmed3f(t, -2.f, 2.f);
  float u = __builtin_fmaf(tc * tc, -0.015625f, 0.125f);
  return tc * __builtin_amdgcn_sqrtf(u);
}

// ---------------- levels 0-2 fused: 32-row blocks, 8 groups x 32 lanes ----------------
// x tile [f][r] swizzled (addr = f*32 + (r ^ (f&31))); params in LDS; partial sums
// exchanged via pbuf[group][out][row] (bank = row: conflict-free).
__global__ __launch_bounds__(256) void ndt_l012(const float* __restrict__ x,
                                                const float4* __restrict__ prm,
                                                const float* __restrict__ cstf,
                                                float* __restrict__ out2) {
  __shared__ float xls[256 * 32];
  __shared__ float4 pl[1812];
  __shared__ float pbuf[8][2][32];
  int tid = threadIdx.x;
  int r = tid & 31, c = tid >> 5;
  int b0 = blockIdx.x * 32;
  for (int i = tid; i < 1812; i += 256) pl[i] = prm[i];
  {
    const float4* xp = (const float4*)(x + (size_t)(b0 + r) * 256 + c * 32);
#pragma unroll
    for (int j = 0; j < 8; ++j) {
      float4 g = xp[j];
      int f = c * 32 + 4 * j;
      xls[(f + 0) * 32 + (r ^ ((4 * j + 0) & 31))] = g.x;
      xls[(f + 1) * 32 + (r ^ ((4 * j + 1) & 31))] = g.y;
      xls[(f + 2) * 32 + (r ^ ((4 * j + 2) & 31))] = g.z;
      xls[(f + 3) * 32 + (r ^ ((4 * j + 3) & 31))] = g.w;
    }
  }
  __syncthreads();
  // ---- L0: group c -> features [c*32, c*32+32)
  float a0 = 0.f, a1 = 0.f;
#pragma unroll
  for (int j = 0; j < 32; ++j) {
    int f = c * 32 + j;
    float xv = xls[f * 32 + (r ^ j)];
    float4 p = pl[f];
    float e = entpair(p.x, xv);
    a0 = __builtin_fmaf(e, p.y, a0);
    a1 = __builtin_fmaf(-e, p.z, a1);
  }
  pbuf[c][0][r] = a0;
  pbuf[c][1][r] = a1;
  __syncthreads();
  float xe1[2];
#pragma unroll
  for (int o = 0; o < 2; ++o) {
    float v = cstf[o];
#pragma unroll
    for (int k = 0; k < 8; ++k) v += pbuf[k][o][r];
    xe1[o] = v;
  }
  __syncthreads();
  // ---- L1: stump c>>2, feature slice (c&3)*64; extras on slice 0
  {
    int s = c >> 2, fs = c & 3;
    const float4* ps = &pl[256 + s * 258];
    a0 = 0.f;
    a1 = 0.f;
#pragma unroll
    for (int j = 0; j < 64; ++j) {
      int f = fs * 64 + j;
      float xv = xls[f * 32 + (r ^ (f & 31))];
      float4 p = ps[f];
      float e = entpair(p.x, xv);
      a0 = __builtin_fmaf(e, p.y, a0);
      a1 = __builtin_fmaf(-e, p.z, a1);
    }
    if (fs == 0) {
#pragma unroll
      for (int o = 0; o < 2; ++o) {
        float4 p = ps[256 + o];
        float e = entpair(p.x, xe1[o]);
        a0 = __builtin_fmaf(e, p.y, a0);
        a1 = __builtin_fmaf(-e, p.z, a1);
      }
    }
    pbuf[c][0][r] = a0;
    pbuf[c][1][r] = a1;
  }
  __syncthreads();
  float xe2[4];
#pragma unroll
  for (int s = 0; s < 2; ++s)
#pragma unroll
    for (int o = 0; o < 2; ++o) {
      float v = cstf[2 + 2 * s + o];
#pragma unroll
      for (int k = 0; k < 4; ++k) v += pbuf[4 * s + k][o][r];
      xe2[2 * s + o] = v;
    }
  __syncthreads();
  // ---- L2: stump c>>1, feature slice (c&1)*128; extras on slice 0
  {
    int s = c >> 1, fs = c & 1;
    const float4* ps = &pl[772 + s * 260];
    a0 = 0.f;
    a1 = 0.f;
#pragma unroll
    for (int j = 0; j < 128; ++j) {
      int f = fs * 128 + j;
      float xv = xls[f * 32 + (r ^ (f & 31))];
      float4 p = ps[f];
      float e = entpair(p.x, xv);
      a0 = __builtin_fmaf(e, p.y, a0);
      a1 = __builtin_fmaf(-e, p.z, a1);
    }
    if (fs == 0) {
#pragma unroll
      for (int o = 0; o < 4; ++o) {
        float4 p = ps[256 + o];
        float e = entpair(p.x, xe2[o]);
        a0 = __builtin_fmaf(e, p.y, a0);
        a1 = __builtin_fmaf(-e, p.z, a1);
      }
    }
    pbuf[c][0][r] = a0;
    pbuf[c][1][r] = a1;
  }
  __syncthreads();
  // ---- reduce L2 -> out2[row][8]; groups 0/1 write float4 halves
  if (c < 2) {
    float o4[4];
#pragma unroll
    for (int i = 0; i < 4; ++i) {
      int s = 2 * c + (i >> 1), o = i & 1;
      float v = cstf[6 + 2 * s + o];
#pragma unroll
      for (int k = 0; k < 2; ++k) v += pbuf[2 * s + k][o][r];
      o4[i] = v;
    }
    *(float4*)(out2 + (size_t)(b0 + r) * 8 + 4 * c) =
        make_float4(o4[0], o4[1], o4[2], o4[3]);
  }
}

// ---------------- big levels (3,4,5): lane <-> row, scalar params ----------
// 256 thr = 4 waves share a 64-row x tile (row-major, f4-chunk xor-swizzled).
// Wave w computes NSW stumps; each lane owns one row: no shuffles, no reduce.
template <int EX, int NSW>
__global__ __launch_bounds__(256) void ndt_big(const float* __restrict__ x,
                                               const float* __restrict__ prev,
                                               const float4* __restrict__ prmL,
                                               const float* __restrict__ cstL,
                                               float* __restrict__ outp,
                                               int outStride) {
  constexpr int FD = 256 + EX;
  __shared__ float xls[64 * 256];
  int tid = threadIdx.x;
  int lane = tid & 63;
  int w = __builtin_amdgcn_readfirstlane(tid >> 6);  // wave id -> SGPR
  int b0 = blockIdx.x * 64;

  // prev-level outputs of this lane's row -> registers
  float pv[EX];
  {
    const float4* pvp = (const float4*)(prev + (size_t)(b0 + lane) * EX);
#pragma unroll
    for (int k = 0; k < EX / 4; ++k) {
      float4 t = pvp[k];
      pv[4 * k] = t.x;
      pv[4 * k + 1] = t.y;
      pv[4 * k + 2] = t.z;
      pv[4 * k + 3] = t.w;
    }
  }
  // stage x rows b0..b0+63: dword addr(row, chunk) = row*256 + 4*(chunk ^ (row&7))
  {
    int row = tid >> 2, cg = tid & 3;
#pragma unroll
    for (int j = 0; j < 16; ++j) {
      int chunk = cg * 16 + j;
      float4 g = *(const float4*)(x + (size_t)(b0 + row) * 256 + chunk * 4);
      *(float4*)&xls[row * 256 + 4 * (chunk ^ (row & 7))] = g;
    }
  }
  __syncthreads();

  int s0 = blockIdx.y * (4 * NSW) + w * NSW;
  const float4* pp = prmL + (size_t)s0 * FD;
  float acc[2 * NSW];
#pragma unroll
  for (int i = 0; i < 2 * NSW; ++i) acc[i] = 0.f;

#pragma unroll 4
  for (int ch = 0; ch < 64; ++ch) {
    float4 xq = *(const float4*)&xls[lane * 256 + 4 * (ch ^ (lane & 7))];
    float xa[4] = {xq.x, xq.y, xq.z, xq.w};
#pragma unroll
    for (int i = 0; i < 4; ++i) {
#pragma unroll
      for (int s = 0; s < NSW; ++s) {
        float4 p = pp[s * FD + 4 * ch + i];
        float e = entpair(p.x, xa[i]);
        acc[2 * s] = __builtin_fmaf(e, p.y, acc[2 * s]);
        acc[2 * s + 1] = __builtin_fmaf(-e, p.z, acc[2 * s + 1]);
      }
    }
  }
  // tail: extra features = prev outputs (registers)
#pragma unroll
  for (int o = 0; o < EX; ++o) {
#pragma unroll
    for (int s = 0; s < NSW; ++s) {
      float4 p = pp[s * FD + 256 + o];
      float e = entpair(p.x, pv[o]);
      acc[2 * s] = __builtin_fmaf(e, p.y, acc[2 * s]);
      acc[2 * s + 1] = __builtin_fmaf(-e, p.z, acc[2 * s + 1]);
    }
  }
#pragma unroll
  for (int s = 0; s < NSW; ++s) {
    acc[2 * s] += cstL[2 * (s0 + s)];
    acc[2 * s + 1] += cstL[2 * (s0 + s) + 1];
  }
  float* op = outp + (size_t)(b0 + lane) * outStride + 2 * s0;
  if (NSW == 2) {
    *(float4*)op = make_float4(acc[0], acc[1], acc[2], acc[3]);
  } else {
    *(float2*)op = make_float2(acc[0], acc[1]);
  }
}

extern "C" void kernel_launch(void* const* d_in, const int* in_sizes, int n_in,
                              void* d_out, int out_size, void* d_ws, size_t ws_size,
                              hipStream_t stream) {
  const float* x = (const float*)d_in[0];
  float* out = (float*)d_out;
  float* wsf = (float*)d_ws;

  // ws layout (float offsets)
  float* out2 = wsf + 0;                   // [8192][8]
  float* out3 = wsf + 65536;               // [8192][16]
  float* out4 = wsf + 196608;              // [8192][32]
  float4* prm = (float4*)(wsf + 458752);   // 17492 float4
  float* cstf = wsf + 528720;              // 126 floats

  MaskArgs ma;
  for (int d = 0; d < 6; ++d) {
    ma.fm[d] = (const float*)d_in[1 + 3 * d];
    ma.cp[d] = (const float*)d_in[2 + 3 * d];
    ma.lr[d] = (const float*)d_in[3 + 3 * d];
  }
  ma.out_masks = out;
  ma.prm = prm;
  ma.cstf = cstf;
  hipLaunchKernelGGL(ndt_masks, dim3(63), dim3(64), 0, stream, ma);

  // levels 0-2 fused
  hipLaunchKernelGGL(ndt_l012, dim3(B_SZ / 32), dim3(256), 0, stream,
                     x, prm, cstf, out2);
  // level 3: 8 stumps; grid (128, 2), 1 stump/wave
  hipLaunchKernelGGL((ndt_big<8, 1>), dim3(B_SZ / 64, 2), dim3(256), 0, stream,
                     x, out2, prm + 1812, cstf + 14, out3, 16);
  // level 4: 16 stumps; grid (128, 4), 1 stump/wave
  hipLaunchKernelGGL((ndt_big<16, 1>), dim3(B_SZ / 64, 4), dim3(256), 0, stream,
                     x, out3, prm + 3924, cstf + 30, out4, 32);
  // level 5: 32 stumps; grid (128, 4), 2 stumps/wave
  hipLaunchKernelGGL((ndt_big<32, 2>), dim3(B_SZ / 64, 4), dim3(256), 0, stream,
                     x, out4, prm + 8276, cstf + 62, out, 64);
}

// Round 6
// 95.029 us; speedup vs baseline: 1.2713x; 1.2713x over previous
//
#include <hip/hip_runtime.h>

#define B_SZ 8192

// ---------------- masks (exact 1.5-entmax via bisection) + fused params ----------------
struct MaskArgs {
  const float* fm[6];
  const float* cp[6];
  const float* lr[6];
  float* out_masks;  // d_out base
  float4* prm;       // fused params {c10, ml0, ml1, 0}
  float* cstf;       // flat per-output 0.5*sum(ml): level d at 2*cstOff[d]
};

__device__ __forceinline__ float wave_max(float v) {
#pragma unroll
  for (int o = 32; o > 0; o >>= 1) v = fmaxf(v, __shfl_xor(v, o));
  return v;
}
__device__ __forceinline__ float wave_sum(float v) {
#pragma unroll
  for (int o = 32; o > 0; o >>= 1) v += __shfl_xor(v, o);
  return v;
}

__global__ __launch_bounds__(64) void ndt_masks(MaskArgs a) {
  const int maskOff[6] = {524288, 524544, 525060, 526100, 528212, 532564};
  const int prmOff[6]  = {0, 256, 772, 1812, 3924, 8276};
  const int cstOff[6]  = {0, 1, 3, 7, 15, 31};
  int bid = blockIdx.x, lane = threadIdx.x;
  int d = 0, s = bid, n = 1;
  while (s >= n) { s -= n; n <<= 1; ++d; }   // level d, stump s, n = 2^d
  int Fd = 256 + ((d > 0) ? n : 0);

  const float* fm = a.fm[d] + (size_t)s * Fd;
  float y[5];
#pragma unroll
  for (int j = 0; j < 5; ++j) {
    int f = lane + 64 * j;
    y[j] = (f < Fd) ? fm[f] * 0.5f : -3.0e38f;
  }
  float m = fmaxf(fmaxf(fmaxf(y[0], y[1]), fmaxf(y[2], y[3])), y[4]);
  m = wave_max(m);
#pragma unroll
  for (int j = 0; j < 5; ++j) y[j] -= m;

  // solve sum clip(y - tau, 0)^2 = 1 ; tau in [-1, 0], strictly decreasing in tau
  float lo = -1.f, hi = 0.f;
  for (int it = 0; it < 24; ++it) {
    float tau = 0.5f * (lo + hi);
    float ss = 0.f;
#pragma unroll
    for (int j = 0; j < 5; ++j) {
      float v = fmaxf(y[j] - tau, 0.f);
      ss = __builtin_fmaf(v, v, ss);
    }
    ss = wave_sum(ss);
    if (ss >= 1.f) lo = tau; else hi = tau;
  }
  float tau = 0.5f * (lo + hi);

  float* mo = a.out_masks + maskOff[d] + (size_t)s * Fd;
  const float* cp = a.cp[d] + (size_t)s * Fd * 2;
  const float* lr = a.lr[d] + (size_t)s * Fd * 2;
  float4* pr = a.prm + prmOff[d] + (size_t)s * Fd;
  float sum0 = 0.f, sum1 = 0.f;
#pragma unroll
  for (int j = 0; j < 5; ++j) {
    int f = lane + 64 * j;
    if (f < Fd) {
      float v = fmaxf(y[j] - tau, 0.f);
      float mk = v * v;
      mo[f] = mk;
      float c0 = cp[2 * f], c1 = cp[2 * f + 1];
      float ml0 = lr[2 * f] * mk, ml1 = lr[2 * f + 1] * mk;
      sum0 += ml0;
      sum1 += ml1;
      pr[f] = make_float4(c1 - c0, ml0, ml1, 0.f);
    }
  }
  sum0 = wave_sum(sum0);
  sum1 = wave_sum(sum1);
  if (lane == 0) {
    a.cstf[2 * (cstOff[d] + s)] = 0.5f * sum0;
    a.cstf[2 * (cstOff[d] + s) + 1] = 0.5f * sum1;
  }
}

// 2-elem entmax15 closed form: t = c10 - x; tc = clamp(t,-2,2);
// e = tc*sqrt(0.125 - tc^2/64); p0 = 0.5+e, p1 = 0.5-e.
__device__ __forceinline__ float entpair(float c10, float xv) {
  float t = c10 - xv;
  float tc = __builtin_amdgcn_fmed3f(t, -2.f, 2.f);
  float u = __builtin_fmaf(tc * tc, -0.015625f, 0.125f);
  return tc * __builtin_amdgcn_sqrtf(u);
}

// ---------------- levels 0-2 fused: 32-row blocks, 8 groups x 32 lanes ----------------
// x tile [f][r] swizzled (addr = f*32 + (r ^ (f&31))); params in LDS; partial sums
// exchanged via pbuf[group][out][row] (bank = row: conflict-free).
__global__ __launch_bounds__(256) void ndt_l012(const float* __restrict__ x,
                                                const float4* __restrict__ prm,
                                                const float* __restrict__ cstf,
                                                float* __restrict__ out2) {
  __shared__ float xls[256 * 32];
  __shared__ float4 pl[1812];
  __shared__ float pbuf[8][2][32];
  int tid = threadIdx.x;
  int r = tid & 31, c = tid >> 5;
  int b0 = blockIdx.x * 32;
  for (int i = tid; i < 1812; i += 256) pl[i] = prm[i];
  {
    const float4* xp = (const float4*)(x + (size_t)(b0 + r) * 256 + c * 32);
#pragma unroll
    for (int j = 0; j < 8; ++j) {
      float4 g = xp[j];
      int f = c * 32 + 4 * j;
      xls[(f + 0) * 32 + (r ^ ((4 * j + 0) & 31))] = g.x;
      xls[(f + 1) * 32 + (r ^ ((4 * j + 1) & 31))] = g.y;
      xls[(f + 2) * 32 + (r ^ ((4 * j + 2) & 31))] = g.z;
      xls[(f + 3) * 32 + (r ^ ((4 * j + 3) & 31))] = g.w;
    }
  }
  __syncthreads();
  // ---- L0: group c -> features [c*32, c*32+32)
  float a0 = 0.f, a1 = 0.f;
#pragma unroll
  for (int j = 0; j < 32; ++j) {
    int f = c * 32 + j;
    float xv = xls[f * 32 + (r ^ j)];
    float4 p = pl[f];
    float e = entpair(p.x, xv);
    a0 = __builtin_fmaf(e, p.y, a0);
    a1 = __builtin_fmaf(-e, p.z, a1);
  }
  pbuf[c][0][r] = a0;
  pbuf[c][1][r] = a1;
  __syncthreads();
  float xe1[2];
#pragma unroll
  for (int o = 0; o < 2; ++o) {
    float v = cstf[o];
#pragma unroll
    for (int k = 0; k < 8; ++k) v += pbuf[k][o][r];
    xe1[o] = v;
  }
  __syncthreads();
  // ---- L1: stump c>>2, feature slice (c&3)*64; extras on slice 0
  {
    int s = c >> 2, fs = c & 3;
    const float4* ps = &pl[256 + s * 258];
    a0 = 0.f;
    a1 = 0.f;
#pragma unroll
    for (int j = 0; j < 64; ++j) {
      int f = fs * 64 + j;
      float xv = xls[f * 32 + (r ^ (f & 31))];
      float4 p = ps[f];
      float e = entpair(p.x, xv);
      a0 = __builtin_fmaf(e, p.y, a0);
      a1 = __builtin_fmaf(-e, p.z, a1);
    }
    if (fs == 0) {
#pragma unroll
      for (int o = 0; o < 2; ++o) {
        float4 p = ps[256 + o];
        float e = entpair(p.x, xe1[o]);
        a0 = __builtin_fmaf(e, p.y, a0);
        a1 = __builtin_fmaf(-e, p.z, a1);
      }
    }
    pbuf[c][0][r] = a0;
    pbuf[c][1][r] = a1;
  }
  __syncthreads();
  float xe2[4];
#pragma unroll
  for (int s = 0; s < 2; ++s)
#pragma unroll
    for (int o = 0; o < 2; ++o) {
      float v = cstf[2 + 2 * s + o];
#pragma unroll
      for (int k = 0; k < 4; ++k) v += pbuf[4 * s + k][o][r];
      xe2[2 * s + o] = v;
    }
  __syncthreads();
  // ---- L2: stump c>>1, feature slice (c&1)*128; extras on slice 0
  {
    int s = c >> 1, fs = c & 1;
    const float4* ps = &pl[772 + s * 260];
    a0 = 0.f;
    a1 = 0.f;
#pragma unroll
    for (int j = 0; j < 128; ++j) {
      int f = fs * 128 + j;
      float xv = xls[f * 32 + (r ^ (f & 31))];
      float4 p = ps[f];
      float e = entpair(p.x, xv);
      a0 = __builtin_fmaf(e, p.y, a0);
      a1 = __builtin_fmaf(-e, p.z, a1);
    }
    if (fs == 0) {
#pragma unroll
      for (int o = 0; o < 4; ++o) {
        float4 p = ps[256 + o];
        float e = entpair(p.x, xe2[o]);
        a0 = __builtin_fmaf(e, p.y, a0);
        a1 = __builtin_fmaf(-e, p.z, a1);
      }
    }
    pbuf[c][0][r] = a0;
    pbuf[c][1][r] = a1;
  }
  __syncthreads();
  // ---- reduce L2 -> out2[row][8]; groups 0/1 write float4 halves
  if (c < 2) {
    float o4[4];
#pragma unroll
    for (int i = 0; i < 4; ++i) {
      int s = 2 * c + (i >> 1), o = i & 1;
      float v = cstf[6 + 2 * s + o];
#pragma unroll
      for (int k = 0; k < 2; ++k) v += pbuf[2 * s + k][o][r];
      o4[i] = v;
    }
    *(float4*)(out2 + (size_t)(b0 + r) * 8 + 4 * c) =
        make_float4(o4[0], o4[1], o4[2], o4[3]);
  }
}

// ---------------- big levels (3,4,5): thread <-> row, params in LDS ----------
// Block: 256 threads = 256 rows, NSW stumps (shared by all threads). Params staged
// in LDS, read as wave-uniform BROADCAST ds_read_b128 (conflict-free). x streamed
// straight from global in 64-B-per-lane chunks (vmcnt path; lgkmcnt = DS only, so
// the compiler can fine-grain both). No shuffles, one barrier.
template <int EX, int NSW>
__global__ __launch_bounds__(256, 4) void ndt_big(const float* __restrict__ x,
                                                  const float* __restrict__ prev,
                                                  const float4* __restrict__ prmL,
                                                  const float* __restrict__ cstL,
                                                  float* __restrict__ outp,
                                                  int outStride) {
  constexpr int FD = 256 + EX;
  __shared__ float4 pl[NSW * FD];
  int tid = threadIdx.x;
  int s0 = blockIdx.y * NSW;
  for (int i = tid; i < NSW * FD; i += 256) pl[i] = prmL[(size_t)s0 * FD + i];

  int row = blockIdx.x * 256 + tid;
  // prev-level outputs of this row -> registers (consecutive 64B chunks: full lines)
  float pv[EX];
  {
    const float4* pvp = (const float4*)(prev + (size_t)row * EX);
#pragma unroll
    for (int k = 0; k < EX / 4; ++k) {
      float4 t = pvp[k];
      pv[4 * k] = t.x;
      pv[4 * k + 1] = t.y;
      pv[4 * k + 2] = t.z;
      pv[4 * k + 3] = t.w;
    }
  }
  __syncthreads();

  float acc[2 * NSW];
#pragma unroll
  for (int i = 0; i < 2 * NSW; ++i) acc[i] = 0.f;

  const float4* xp = (const float4*)(x + (size_t)row * 256);
#pragma unroll 2
  for (int g = 0; g < 16; ++g) {
    float4 xq[4];
#pragma unroll
    for (int q = 0; q < 4; ++q) xq[q] = xp[4 * g + q];
#pragma unroll
    for (int q = 0; q < 4; ++q) {
      float xa[4] = {xq[q].x, xq[q].y, xq[q].z, xq[q].w};
#pragma unroll
      for (int i = 0; i < 4; ++i) {
#pragma unroll
        for (int s = 0; s < NSW; ++s) {
          float4 p = pl[s * FD + 16 * g + 4 * q + i];  // uniform -> broadcast
          float e = entpair(p.x, xa[i]);
          acc[2 * s] = __builtin_fmaf(e, p.y, acc[2 * s]);
          acc[2 * s + 1] = __builtin_fmaf(-e, p.z, acc[2 * s + 1]);
        }
      }
    }
  }
  // tail: extra features = prev outputs (registers)
#pragma unroll
  for (int o = 0; o < EX; ++o) {
#pragma unroll
    for (int s = 0; s < NSW; ++s) {
      float4 p = pl[s * FD + 256 + o];
      float e = entpair(p.x, pv[o]);
      acc[2 * s] = __builtin_fmaf(e, p.y, acc[2 * s]);
      acc[2 * s + 1] = __builtin_fmaf(-e, p.z, acc[2 * s + 1]);
    }
  }
#pragma unroll
  for (int s = 0; s < NSW; ++s) {
    acc[2 * s] += cstL[2 * (s0 + s)];
    acc[2 * s + 1] += cstL[2 * (s0 + s) + 1];
  }
  float* op = outp + (size_t)row * outStride + 2 * s0;
  if (NSW == 2) {
    *(float4*)op = make_float4(acc[0], acc[1], acc[2], acc[3]);
  } else {
    *(float2*)op = make_float2(acc[0], acc[1]);
  }
}

extern "C" void kernel_launch(void* const* d_in, const int* in_sizes, int n_in,
                              void* d_out, int out_size, void* d_ws, size_t ws_size,
                              hipStream_t stream) {
  const float* x = (const float*)d_in[0];
  float* out = (float*)d_out;
  float* wsf = (float*)d_ws;

  // ws layout (float offsets)
  float* out2 = wsf + 0;                   // [8192][8]
  float* out3 = wsf + 65536;               // [8192][16]
  float* out4 = wsf + 196608;              // [8192][32]
  float4* prm = (float4*)(wsf + 458752);   // 17492 float4
  float* cstf = wsf + 528720;              // 126 floats

  MaskArgs ma;
  for (int d = 0; d < 6; ++d) {
    ma.fm[d] = (const float*)d_in[1 + 3 * d];
    ma.cp[d] = (const float*)d_in[2 + 3 * d];
    ma.lr[d] = (const float*)d_in[3 + 3 * d];
  }
  ma.out_masks = out;
  ma.prm = prm;
  ma.cstf = cstf;
  hipLaunchKernelGGL(ndt_masks, dim3(63), dim3(64), 0, stream, ma);

  // levels 0-2 fused
  hipLaunchKernelGGL(ndt_l012, dim3(B_SZ / 32), dim3(256), 0, stream,
                     x, prm, cstf, out2);
  // level 3: 8 stumps; grid (32 rowblks, 8 stump-groups), NSW=1
  hipLaunchKernelGGL((ndt_big<8, 1>), dim3(B_SZ / 256, 8), dim3(256), 0, stream,
                     x, out2, prm + 1812, cstf + 14, out3, 16);
  // level 4: 16 stumps; grid (32, 16), NSW=1
  hipLaunchKernelGGL((ndt_big<16, 1>), dim3(B_SZ / 256, 16), dim3(256), 0, stream,
                     x, out3, prm + 3924, cstf + 30, out4, 32);
  // level 5: 32 stumps; grid (32, 16), NSW=2
  hipLaunchKernelGGL((ndt_big<32, 2>), dim3(B_SZ / 256, 16), dim3(256), 0, stream,
                     x, out4, prm + 8276, cstf + 62, out, 64);
}